// Round 8
// baseline (649.514 us; speedup 1.0000x reference)
//
#include <hip/hip_runtime.h>

typedef short v8s __attribute__((ext_vector_type(8)));
typedef float v4f __attribute__((ext_vector_type(4)));
typedef unsigned short v4u __attribute__((ext_vector_type(4)));

#define MFMA(a,b,c) __builtin_amdgcn_mfma_f32_16x16x32_bf16((a),(b),(c),0,0,0)

__device__ __forceinline__ unsigned short f2b(float f) {
  unsigned int x = __builtin_bit_cast(unsigned int, f);
  x += 0x7fffu + ((x >> 16) & 1u);
  return (unsigned short)(x >> 16);
}

__device__ __forceinline__ float b2f(unsigned short u) {
  unsigned int x = ((unsigned int)u) << 16;
  return __builtin_bit_cast(float, x);
}

__device__ __forceinline__ float gelu_exact(float v) {
  return 0.5f * v * (1.0f + erff(v * 0.70710678118654752f));
}

// fast GELU (tanh form via sigmoid): max |err| ~3e-4, << bf16 rounding of y
__device__ __forceinline__ float gelu_fast(float v) {
  float u = 1.5957691f * v * (1.0f + 0.044715f * v * v);
  return v * (1.0f / (1.0f + __expf(-u)));
}

// ---------------- prep: weight bf16 conversion + bias MLP ----------------
__global__ void prep_kernel(const float* __restrict__ wqkv, const float* __restrict__ whead,
                            const float* __restrict__ wc1, const float* __restrict__ wc2,
                            const float* __restrict__ delta, const int* __restrict__ indexv,
                            const float* __restrict__ wb1, const float* __restrict__ bb1,
                            const float* __restrict__ wb2, const float* __restrict__ bb2,
                            unsigned short* __restrict__ wqkv_b, unsigned short* __restrict__ whead_b,
                            unsigned short* __restrict__ wc1_b, unsigned short* __restrict__ w2r_b,
                            float* __restrict__ bias_ws) {
  int i = blockIdx.x * 256 + threadIdx.x;
  if (i < 49152) { wqkv_b[i] = f2b(wqkv[i]); return; }
  i -= 49152;
  if (i < 16384) { whead_b[i] = f2b(whead[i]); return; }
  i -= 16384;
  if (i < 16384) { wc1_b[i] = f2b(wc1[i]); return; }
  i -= 16384;
  if (i < 147456) {
    // dst layout: w2r[o*1152 + (ky*3+kx)*128 + c]; src: wc2[o*1152 + c*9 + (ky*3+kx)]
    int o = i / 1152; int rem = i - o * 1152; int pos = rem >> 7; int c = rem & 127;
    w2r_b[i] = f2b(wc2[o * 1152 + c * 9 + pos]);
    return;
  }
  i -= 147456;
  if (i < 4096) {
    int u = indexv[i];
    float d0 = delta[2 * u], d1 = delta[2 * u + 1];
    float acc = bb2[0];
    #pragma unroll
    for (int j = 0; j < 16; ++j) {
      float t = d0 * wb1[2 * j] + d1 * wb1[2 * j + 1] + bb1[j];
      acc += gelu_exact(t) * wb2[j];
    }
    bias_ws[i] = acc;
  }
}

// ---------------- x BCHW fp32 -> NHWC bf16 transpose ----------------
__global__ __launch_bounds__(256, 2) void xt_kernel(
    const float* __restrict__ x, unsigned short* __restrict__ t16) {
  __shared__ unsigned short T[256 * 129];  // [px][c], odd stride (66048 B)
  const int tid = threadIdx.x;
  const int bid = blockIdx.x;              // 1024 = 4 batches x 256 rows
  const int b = bid >> 8, h = bid & 255;
  const float* src = x + (size_t)b * 128 * 65536 + h * 256;

  #pragma unroll
  for (int it = 0; it < 32; ++it) {
    int u = it * 256 + tid;                // 8192 float4 units
    int c = u >> 6, w4 = u & 63;           // wave: fixed c, w4 0..63 -> 1KB dense
    float4 v = *(const float4*)(src + (size_t)c * 65536 + w4 * 4);
    int base = (w4 * 4) * 129 + c;
    T[base]       = f2b(v.x);
    T[base + 129] = f2b(v.y);
    T[base + 258] = f2b(v.z);
    T[base + 387] = f2b(v.w);
  }
  __syncthreads();

  unsigned short* dst = t16 + (size_t)((b * 256 + h) * 256) * 128;
  #pragma unroll
  for (int it = 0; it < 16; ++it) {
    int idx = it * 256 + tid;              // 4096 v8s units
    int px = idx >> 4, c8 = idx & 15;      // wave: 4 px x 256B = 1KB dense
    const unsigned short* t = &T[px * 129 + c8 * 8];
    v8s o;
    #pragma unroll
    for (int j = 0; j < 8; ++j) o[j] = (short)t[j];
    *(v8s*)(dst + px * 128 + c8 * 8) = o;
  }
}

// ---------------- fused window-attention ----------------
// one block (256 thr) per 8x8 window; reads bf16(x) from t16 (dense NHWC),
// overwrites its own t16 window with x1 (bf16). conv1 moved to conv2.
// LDS: XS aliases VT -> 53248 B -> 3 blocks/CU.
__global__ __launch_bounds__(256, 3) void attn_kernel(
    const float* __restrict__ bias,
    const unsigned short* __restrict__ wqkv_b, const unsigned short* __restrict__ whead_b,
    const float* __restrict__ bqkv, const float* __restrict__ bhead,
    unsigned short* __restrict__ t16) {
  __shared__ unsigned short U0[128 * 72];   // VT [c][token]  (18432 B)
                                            // aliased: XS [token][136] bf16 x, later bf16 x1
  __shared__ unsigned short QP[64 * 136];   // Q [token][c]; later P [token][h*64+m]
  __shared__ unsigned short KO[64 * 136];   // K [token][c]; later O [token][c]
  unsigned short* const XS = U0;
  unsigned short* const VT = U0;

  const int tid = threadIdx.x;
  const int wv = tid >> 6, lane = tid & 63, quad = lane >> 4, l15 = lane & 15;
  // XCD-aware swizzle: grid 4096 = 8 XCDs x 512 contiguous windows each
  const int bid0 = blockIdx.x;
  const int bid = ((bid0 & 7) << 9) | (bid0 >> 3);
  const int bb = bid >> 10, rem = bid & 1023;
  const int h0 = (rem >> 5) * 8, w0 = (rem & 31) * 8;

  // phase 0: load x window (bf16 NHWC) -> XS, dense 16B/lane
  #pragma unroll
  for (int it = 0; it < 4; ++it) {
    int idx = it * 256 + tid;
    int token = idx >> 4, c8 = idx & 15;
    int py = token >> 3, px = token & 7;
    *(v8s*)(&XS[token * 136 + c8 * 8]) =
        *(const v8s*)(t16 + (size_t)((bb * 256 + h0 + py) * 256 + w0 + px) * 128 + c8 * 8);
  }
  __syncthreads();

  // phase 1: QKV GEMM (M = out-channel, N = token, K = c)
  v4u vpk[2][4];
  #pragma unroll
  for (int part = 0; part < 3; ++part) {
    v4f acc[2][4] = {};
    #pragma unroll
    for (int ks = 0; ks < 4; ++ks) {
      v8s afr[2];
      #pragma unroll
      for (int i = 0; i < 2; ++i)
        afr[i] = *(const v8s*)(wqkv_b + (size_t)(part * 128 + (2 * wv + i) * 16 + l15) * 128 + ks * 32 + quad * 8);
      v8s bfr[4];
      #pragma unroll
      for (int ct = 0; ct < 4; ++ct)
        bfr[ct] = *(const v8s*)(&XS[(ct * 16 + l15) * 136 + ks * 32 + quad * 8]);
      #pragma unroll
      for (int i = 0; i < 2; ++i)
        #pragma unroll
        for (int ct = 0; ct < 4; ++ct)
          acc[i][ct] = MFMA(afr[i], bfr[ct], acc[i][ct]);
    }
    #pragma unroll
    for (int i = 0; i < 2; ++i) {
      int ol0 = (2 * wv + i) * 16 + quad * 4;
      float4 bq = *(const float4*)(bqkv + part * 128 + ol0);
      float bqa[4] = {bq.x, bq.y, bq.z, bq.w};
      #pragma unroll
      for (int ct = 0; ct < 4; ++ct) {
        int token = ct * 16 + l15;
        v4u pk = {f2b(acc[i][ct][0] + bqa[0]), f2b(acc[i][ct][1] + bqa[1]),
                  f2b(acc[i][ct][2] + bqa[2]), f2b(acc[i][ct][3] + bqa[3])};
        if (part == 0)      *(v4u*)(&QP[token * 136 + ol0]) = pk;
        else if (part == 1) *(v4u*)(&KO[token * 136 + ol0]) = pk;
        else                vpk[i][ct] = pk;
      }
    }
  }
  __syncthreads();  // all XS reads done; QP/KO published

  // write V^T over the XS region (overlaps phase 2, published by its barrier)
  #pragma unroll
  for (int i = 0; i < 2; ++i) {
    int ol0 = (2 * wv + i) * 16 + quad * 4;
    #pragma unroll
    for (int ct = 0; ct < 4; ++ct) {
      int token = ct * 16 + l15;
      VT[(ol0 + 0) * 72 + token] = vpk[i][ct][0];
      VT[(ol0 + 1) * 72 + token] = vpk[i][ct][1];
      VT[(ol0 + 2) * 72 + token] = vpk[i][ct][2];
      VT[(ol0 + 3) * 72 + token] = vpk[i][ct][3];
    }
  }

  // phase 2: scores + softmax (wave w owns query tokens 16w..16w+15)
  const int t0 = wv * 16;
  v4f sc[2][4] = {};
  #pragma unroll
  for (int h = 0; h < 2; ++h)
    #pragma unroll
    for (int ks = 0; ks < 2; ++ks) {
      v8s afr = *(const v8s*)(&QP[(t0 + l15) * 136 + h * 64 + ks * 32 + quad * 8]);
      #pragma unroll
      for (int ct = 0; ct < 4; ++ct) {
        v8s bfr = *(const v8s*)(&KO[(ct * 16 + l15) * 136 + h * 64 + ks * 32 + quad * 8]);
        sc[h][ct] = MFMA(afr, bfr, sc[h][ct]);
      }
    }
  float linv[2][4];
  const int rowbase = (t0 + quad * 4) * 64 + l15;
  #pragma unroll
  for (int h = 0; h < 2; ++h) {
    float sv[4][4];
    #pragma unroll
    for (int ct = 0; ct < 4; ++ct)
      #pragma unroll
      for (int r = 0; r < 4; ++r)
        sv[ct][r] = sc[h][ct][r] * 0.125f + bias[rowbase + r * 64 + ct * 16];
    #pragma unroll
    for (int r = 0; r < 4; ++r) {
      float m = fmaxf(fmaxf(sv[0][r], sv[1][r]), fmaxf(sv[2][r], sv[3][r]));
      m = fmaxf(m, __shfl_xor(m, 1, 16));
      m = fmaxf(m, __shfl_xor(m, 2, 16));
      m = fmaxf(m, __shfl_xor(m, 4, 16));
      m = fmaxf(m, __shfl_xor(m, 8, 16));
      float s = 0.f;
      #pragma unroll
      for (int ct = 0; ct < 4; ++ct) { float p = __expf(sv[ct][r] - m); sv[ct][r] = p; s += p; }
      s += __shfl_xor(s, 1, 16);
      s += __shfl_xor(s, 2, 16);
      s += __shfl_xor(s, 4, 16);
      s += __shfl_xor(s, 8, 16);
      linv[h][r] = 1.0f / s;
    }
    #pragma unroll
    for (int ct = 0; ct < 4; ++ct)
      #pragma unroll
      for (int r = 0; r < 4; ++r)
        QP[(t0 + quad * 4 + r) * 136 + h * 64 + ct * 16 + l15] = f2b(sv[ct][r]);
  }
  __syncthreads();  // protects K->O aliasing; publishes VT and P

  // phase 3: O = (P @ V) * 1/l
  v4f ov[2][4] = {};
  #pragma unroll
  for (int h = 0; h < 2; ++h)
    #pragma unroll
    for (int ks = 0; ks < 2; ++ks) {
      v8s afr = *(const v8s*)(&QP[(t0 + l15) * 136 + h * 64 + ks * 32 + quad * 8]);
      #pragma unroll
      for (int ct = 0; ct < 4; ++ct) {
        v8s bfr = *(const v8s*)(&VT[(h * 64 + ct * 16 + l15) * 72 + ks * 32 + quad * 8]);
        ov[h][ct] = MFMA(afr, bfr, ov[h][ct]);
      }
    }
  #pragma unroll
  for (int h = 0; h < 2; ++h)
    #pragma unroll
    for (int ct = 0; ct < 4; ++ct)
      #pragma unroll
      for (int r = 0; r < 4; ++r)
        KO[(t0 + quad * 4 + r) * 136 + h * 64 + ct * 16 + l15] = f2b(ov[h][ct][r] * linv[h][r]);
  // (wave-local: own rows written after own reads; DS in-order per wave)
  __syncthreads();  // all VT reads done before XS (same memory) is overwritten

  // phase 4: head projection + residual (bf16 x from t16, L2-hot); x1 -> XS
  v4f pj[8] = {};
  #pragma unroll
  for (int ks = 0; ks < 4; ++ks) {
    v8s afr = *(const v8s*)(&KO[(t0 + l15) * 136 + ks * 32 + quad * 8]);
    #pragma unroll
    for (int ct = 0; ct < 8; ++ct) {
      v8s bfr = *(const v8s*)(whead_b + (size_t)(ct * 16 + l15) * 128 + ks * 32 + quad * 8);
      pj[ct] = MFMA(afr, bfr, pj[ct]);
    }
  }
  {
    int token0 = t0 + quad * 4;
    int py = token0 >> 3, px = token0 & 7;
    const unsigned short* xtw = t16 + (size_t)((bb * 256 + h0 + py) * 256 + w0 + px) * 128;
    #pragma unroll
    for (int ct = 0; ct < 8; ++ct) {
      int o = ct * 16 + l15;
      float bh = bhead[o];
      #pragma unroll
      for (int r = 0; r < 4; ++r) {
        float xa = b2f(xtw[(size_t)r * 128 + o]);
        XS[(token0 + r) * 136 + o] = f2b(xa + pj[ct][r] + bh);
      }
    }
  }
  __syncthreads();  // all xt reads + XS writes done before the in-place dump

  // dump x1 (bf16 NHWC) over this block's own t16 window (dense 16B/lane)
  #pragma unroll
  for (int it = 0; it < 4; ++it) {
    int idx = it * 256 + tid;
    int token = idx >> 4, c8 = idx & 15;
    int py = token >> 3, px = token & 7;
    *(v8s*)(t16 + (size_t)((bb * 256 + h0 + py) * 256 + w0 + px) * 128 + c8 * 8) =
        *(const v8s*)(&XS[token * 136 + c8 * 8]);
  }
}

// ------- fused conv1(1x1)+GELU + conv2(3x3, edge pad) + LeakyReLU + residual -------
// Tile = 32w x 2h x 128c. Loads x1 halo (136 px) from t16, recomputes
// y = gelu(W1.x1 + b1) in-kernel with fast GELU (no erff), 3x3 MFMA loop.
// LDS: YH ALIASES XH (all XH reads land in yacc regs before the barrier)
// -> 39168 B -> 4 blocks/CU. Direct BCHW fp32 stores (full lines per block).
__global__ __launch_bounds__(256, 4) void conv2_kernel(
    const unsigned short* __restrict__ w2r, const unsigned short* __restrict__ wc1_b,
    const unsigned short* __restrict__ t16,
    const float* __restrict__ bc1, const float* __restrict__ bc2, float* __restrict__ xo) {
  __shared__ unsigned short XH[144 * 136];  // x1 halo [px][c]; later y halo (39168 B)
  unsigned short* const YH = XH;            // alias (see barrier discipline below)
  const int tid = threadIdx.x;
  const int wv = tid >> 6, lane = tid & 63, quad = lane >> 4, l15 = lane & 15;
  const int bid0 = blockIdx.x;
  const int bid = ((bid0 & 7) << 9) | (bid0 >> 3);  // XCD swizzle (4096 = 8x512)
  const int bb = bid >> 10, rem = bid & 1023;
  const int y0 = (rem >> 3) * 2, x0 = (rem & 7) * 32;

  // prefetch x1 residual (bf16 NHWC): 4 consecutive channels per (i,ct)
  v4u xpre[2][4];
  #pragma unroll
  for (int i = 0; i < 2; ++i) {
    int o0 = (2 * wv + i) * 16 + quad * 4;
    #pragma unroll
    for (int ct = 0; ct < 4; ++ct) {
      int pix = ct * 16 + l15, typ = pix >> 5, txp = pix & 31;
      xpre[i][ct] = *(const v4u*)(t16 + (size_t)((bb * 256 + y0 + typ) * 256 + x0 + txp) * 128 + o0);
    }
  }

  // x1 halo load: 4 rows x 34 px x 128 ch (edge-clamped), 2176 8ch-units
  for (int it = 0; it < 9; ++it) {
    int idx = it * 256 + tid;
    if (idx < 2176) {
      int hp = idx >> 4, c8 = idx & 15;
      int iy = hp / 34, ix = hp - iy * 34;
      int hy = y0 - 1 + iy; hy = hy < 0 ? 0 : (hy > 255 ? 255 : hy);
      int hx = x0 - 1 + ix; hx = hx < 0 ? 0 : (hx > 255 ? 255 : hx);
      *(v8s*)(&XH[hp * 136 + c8 * 8]) =
          *(const v8s*)(t16 + (size_t)((bb * 256 + hy) * 256 + hx) * 128 + c8 * 8);
    }
  }
  __syncthreads();

  // conv1: yacc[o][px] = W1.x1 for all 136 halo px (9 px-tiles of 16).
  // All XH reads complete here (into registers) before YH overwrites XH.
  v4f yacc[2][9] = {};
  #pragma unroll
  for (int ks = 0; ks < 4; ++ks) {
    v8s afr[2];
    #pragma unroll
    for (int i = 0; i < 2; ++i)
      afr[i] = *(const v8s*)(wc1_b + (size_t)((2 * wv + i) * 16 + l15) * 128 + ks * 32 + quad * 8);
    v8s bfr[9];
    #pragma unroll
    for (int ct = 0; ct < 9; ++ct)
      bfr[ct] = *(const v8s*)(&XH[(ct * 16 + l15) * 136 + ks * 32 + quad * 8]);
    #pragma unroll
    for (int i = 0; i < 2; ++i)
      #pragma unroll
      for (int ct = 0; ct < 9; ++ct)
        yacc[i][ct] = MFMA(afr[i], bfr[ct], yacc[i][ct]);
  }
  __syncthreads();  // all XH reads drained; safe to overwrite with y

  #pragma unroll
  for (int i = 0; i < 2; ++i) {
    int ol0 = (2 * wv + i) * 16 + quad * 4;
    float4 bq = *(const float4*)(bc1 + ol0);
    float bqa[4] = {bq.x, bq.y, bq.z, bq.w};
    #pragma unroll
    for (int ct = 0; ct < 9; ++ct) {
      int token = ct * 16 + l15;   // <=143, fits buffer
      v4u pk = {f2b(gelu_fast(yacc[i][ct][0] + bqa[0])),
                f2b(gelu_fast(yacc[i][ct][1] + bqa[1])),
                f2b(gelu_fast(yacc[i][ct][2] + bqa[2])),
                f2b(gelu_fast(yacc[i][ct][3] + bqa[3]))};
      *(v4u*)(&YH[token * 136 + ol0]) = pk;
    }
  }
  __syncthreads();

  // conv2 3x3 over YH
  v4f acc[2][4] = {};
  int bct[4];
  #pragma unroll
  for (int ct = 0; ct < 4; ++ct) {
    int pix = ct * 16 + l15, typ = pix >> 5, txp = pix & 31;
    bct[ct] = (typ * 34 + txp) * 136 + quad * 8;
  }
  const unsigned short* wb0 = w2r + (size_t)((2 * wv + 0) * 16 + l15) * 1152 + quad * 8;
  const unsigned short* wb1 = w2r + (size_t)((2 * wv + 1) * 16 + l15) * 1152 + quad * 8;
  #pragma unroll
  for (int ks = 0; ks < 36; ++ks) {
    const int pos = ks >> 2, cb = ks & 3;
    const int ky = pos / 3, kx = pos - ky * 3;
    const int koff = (ky * 34 + kx) * 136 + cb * 32;
    v8s a0 = *(const v8s*)(wb0 + ks * 32);
    v8s a1 = *(const v8s*)(wb1 + ks * 32);
    #pragma unroll
    for (int ct = 0; ct < 4; ++ct) {
      v8s bfr = *(const v8s*)(&YH[bct[ct] + koff]);
      acc[0][ct] = MFMA(a0, bfr, acc[0][ct]);
      acc[1][ct] = MFMA(a1, bfr, acc[1][ct]);
    }
  }

  // epilogue: bias + leaky + bf16 residual, store straight from registers.
  #pragma unroll
  for (int i = 0; i < 2; ++i) {
    int o0 = (2 * wv + i) * 16 + quad * 4;
    float4 bc = *(const float4*)(bc2 + o0);
    float bca[4] = {bc.x, bc.y, bc.z, bc.w};
    #pragma unroll
    for (int ct = 0; ct < 4; ++ct) {
      int pix = ct * 16 + l15, typ = pix >> 5, txp = pix & 31;
      float* po = xo + (size_t)(bb * 128 + o0) * 65536 + (y0 + typ) * 256 + (x0 + txp);
      #pragma unroll
      for (int r = 0; r < 4; ++r) {
        float v = acc[i][ct][r] + bca[r];
        v = v > 0.f ? v : 0.1f * v;
        po[(size_t)r * 65536] = v + b2f(xpre[i][ct][r]);
      }
    }
  }
}

extern "C" void kernel_launch(void* const* d_in, const int* in_sizes, int n_in,
                              void* d_out, int out_size, void* d_ws, size_t ws_size,
                              hipStream_t stream) {
  (void)in_sizes; (void)n_in; (void)out_size; (void)ws_size;
  const float* x      = (const float*)d_in[0];
  const float* delta  = (const float*)d_in[1];
  const int*   indexv = (const int*)d_in[2];
  const float* w_qkv  = (const float*)d_in[3];
  const float* b_qkv  = (const float*)d_in[4];
  const float* w_head = (const float*)d_in[5];
  const float* b_head = (const float*)d_in[6];
  const float* w_b1   = (const float*)d_in[7];
  const float* b_b1   = (const float*)d_in[8];
  const float* w_b2   = (const float*)d_in[9];
  const float* b_b2   = (const float*)d_in[10];
  const float* w_c1   = (const float*)d_in[11];
  const float* b_c1   = (const float*)d_in[12];
  const float* w_c2   = (const float*)d_in[13];
  const float* b_c2   = (const float*)d_in[14];
  float* out = (float*)d_out;

  char* ws = (char*)d_ws;
  float*          bias_ws = (float*)(ws + 0);                 //  16384 B
  unsigned short* wqkv_b  = (unsigned short*)(ws + 16384);    //  98304 B
  unsigned short* whead_b = (unsigned short*)(ws + 114688);   //  32768 B
  unsigned short* wc1_b   = (unsigned short*)(ws + 147456);   //  32768 B
  unsigned short* w2r_b   = (unsigned short*)(ws + 180224);   // 294912 B
  unsigned short* t16     = (unsigned short*)(ws + 475136 + 67108864); // 67108864 B: bf16(x) -> x1

  prep_kernel<<<912, 256, 0, stream>>>(w_qkv, w_head, w_c1, w_c2, delta, indexv,
                                       w_b1, b_b1, w_b2, b_b2,
                                       wqkv_b, whead_b, wc1_b, w2r_b, bias_ws);
  xt_kernel<<<1024, 256, 0, stream>>>(x, t16);
  attn_kernel<<<4096, 256, 0, stream>>>(bias_ws, wqkv_b, whead_b,
                                        b_qkv, b_head, t16);
  conv2_kernel<<<4096, 256, 0, stream>>>(w2r_b, wc1_b, t16, b_c1, b_c2, out);
}

// Round 9
// 572.613 us; speedup vs baseline: 1.1343x; 1.1343x over previous
//
#include <hip/hip_runtime.h>

typedef short v8s __attribute__((ext_vector_type(8)));
typedef float v4f __attribute__((ext_vector_type(4)));
typedef unsigned short v4u __attribute__((ext_vector_type(4)));

#define MFMA(a,b,c) __builtin_amdgcn_mfma_f32_16x16x32_bf16((a),(b),(c),0,0,0)

__device__ __forceinline__ unsigned short f2b(float f) {
  unsigned int x = __builtin_bit_cast(unsigned int, f);
  x += 0x7fffu + ((x >> 16) & 1u);
  return (unsigned short)(x >> 16);
}

__device__ __forceinline__ float b2f(unsigned short u) {
  unsigned int x = ((unsigned int)u) << 16;
  return __builtin_bit_cast(float, x);
}

__device__ __forceinline__ float gelu_exact(float v) {
  return 0.5f * v * (1.0f + erff(v * 0.70710678118654752f));
}

// fast GELU (tanh form via sigmoid): max |err| ~3e-4, << bf16 rounding of y
__device__ __forceinline__ float gelu_fast(float v) {
  float u = 1.5957691f * v * (1.0f + 0.044715f * v * v);
  return v * (1.0f / (1.0f + __expf(-u)));
}

// ---------------- prep: weight bf16 conversion + bias MLP ----------------
__global__ void prep_kernel(const float* __restrict__ wqkv, const float* __restrict__ whead,
                            const float* __restrict__ wc1, const float* __restrict__ wc2,
                            const float* __restrict__ delta, const int* __restrict__ indexv,
                            const float* __restrict__ wb1, const float* __restrict__ bb1,
                            const float* __restrict__ wb2, const float* __restrict__ bb2,
                            unsigned short* __restrict__ wqkv_b, unsigned short* __restrict__ whead_b,
                            unsigned short* __restrict__ wc1_b, unsigned short* __restrict__ w2r_b,
                            float* __restrict__ bias_ws) {
  int i = blockIdx.x * 256 + threadIdx.x;
  if (i < 49152) { wqkv_b[i] = f2b(wqkv[i]); return; }
  i -= 49152;
  if (i < 16384) { whead_b[i] = f2b(whead[i]); return; }
  i -= 16384;
  if (i < 16384) { wc1_b[i] = f2b(wc1[i]); return; }
  i -= 16384;
  if (i < 147456) {
    // dst layout: w2r[o*1152 + (ky*3+kx)*128 + c]; src: wc2[o*1152 + c*9 + (ky*3+kx)]
    int o = i / 1152; int rem = i - o * 1152; int pos = rem >> 7; int c = rem & 127;
    w2r_b[i] = f2b(wc2[o * 1152 + c * 9 + pos]);
    return;
  }
  i -= 147456;
  if (i < 4096) {
    int u = indexv[i];
    float d0 = delta[2 * u], d1 = delta[2 * u + 1];
    float acc = bb2[0];
    #pragma unroll
    for (int j = 0; j < 16; ++j) {
      float t = d0 * wb1[2 * j] + d1 * wb1[2 * j + 1] + bb1[j];
      acc += gelu_exact(t) * wb2[j];
    }
    bias_ws[i] = acc;
  }
}

// ---------------- x BCHW fp32 -> NHWC bf16 transpose ----------------
__global__ __launch_bounds__(256, 2) void xt_kernel(
    const float* __restrict__ x, unsigned short* __restrict__ t16) {
  __shared__ unsigned short T[256 * 129];  // [px][c], odd stride (66048 B)
  const int tid = threadIdx.x;
  const int bid = blockIdx.x;              // 1024 = 4 batches x 256 rows
  const int b = bid >> 8, h = bid & 255;
  const float* src = x + (size_t)b * 128 * 65536 + h * 256;

  #pragma unroll
  for (int it = 0; it < 32; ++it) {
    int u = it * 256 + tid;                // 8192 float4 units
    int c = u >> 6, w4 = u & 63;           // wave: fixed c, w4 0..63 -> 1KB dense
    float4 v = *(const float4*)(src + (size_t)c * 65536 + w4 * 4);
    int base = (w4 * 4) * 129 + c;
    T[base]       = f2b(v.x);
    T[base + 129] = f2b(v.y);
    T[base + 258] = f2b(v.z);
    T[base + 387] = f2b(v.w);
  }
  __syncthreads();

  unsigned short* dst = t16 + (size_t)((b * 256 + h) * 256) * 128;
  #pragma unroll
  for (int it = 0; it < 16; ++it) {
    int idx = it * 256 + tid;              // 4096 v8s units
    int px = idx >> 4, c8 = idx & 15;      // wave: 4 px x 256B = 1KB dense
    const unsigned short* t = &T[px * 129 + c8 * 8];
    v8s o;
    #pragma unroll
    for (int j = 0; j < 8; ++j) o[j] = (short)t[j];
    *(v8s*)(dst + px * 128 + c8 * 8) = o;
  }
}

// ---------------- fused window-attention ----------------
// one block (256 thr) per 8x8 window; reads bf16(x) from t16 (dense NHWC),
// overwrites its own t16 window with x1 (bf16). conv1 moved to conv2.
// LDS: XS aliases VT -> 53248 B -> 3 blocks/CU.
__global__ __launch_bounds__(256, 3) void attn_kernel(
    const float* __restrict__ bias,
    const unsigned short* __restrict__ wqkv_b, const unsigned short* __restrict__ whead_b,
    const float* __restrict__ bqkv, const float* __restrict__ bhead,
    unsigned short* __restrict__ t16) {
  __shared__ unsigned short U0[128 * 72];   // VT [c][token]  (18432 B)
                                            // aliased: XS [token][136] bf16 x, later bf16 x1
  __shared__ unsigned short QP[64 * 136];   // Q [token][c]; later P [token][h*64+m]
  __shared__ unsigned short KO[64 * 136];   // K [token][c]; later O [token][c]
  unsigned short* const XS = U0;
  unsigned short* const VT = U0;

  const int tid = threadIdx.x;
  const int wv = tid >> 6, lane = tid & 63, quad = lane >> 4, l15 = lane & 15;
  // XCD-aware swizzle: grid 4096 = 8 XCDs x 512 contiguous windows each
  const int bid0 = blockIdx.x;
  const int bid = ((bid0 & 7) << 9) | (bid0 >> 3);
  const int bb = bid >> 10, rem = bid & 1023;
  const int h0 = (rem >> 5) * 8, w0 = (rem & 31) * 8;

  // phase 0: load x window (bf16 NHWC) -> XS, dense 16B/lane
  #pragma unroll
  for (int it = 0; it < 4; ++it) {
    int idx = it * 256 + tid;
    int token = idx >> 4, c8 = idx & 15;
    int py = token >> 3, px = token & 7;
    *(v8s*)(&XS[token * 136 + c8 * 8]) =
        *(const v8s*)(t16 + (size_t)((bb * 256 + h0 + py) * 256 + w0 + px) * 128 + c8 * 8);
  }
  __syncthreads();

  // phase 1: QKV GEMM (M = out-channel, N = token, K = c)
  v4u vpk[2][4];
  #pragma unroll
  for (int part = 0; part < 3; ++part) {
    v4f acc[2][4] = {};
    #pragma unroll
    for (int ks = 0; ks < 4; ++ks) {
      v8s afr[2];
      #pragma unroll
      for (int i = 0; i < 2; ++i)
        afr[i] = *(const v8s*)(wqkv_b + (size_t)(part * 128 + (2 * wv + i) * 16 + l15) * 128 + ks * 32 + quad * 8);
      v8s bfr[4];
      #pragma unroll
      for (int ct = 0; ct < 4; ++ct)
        bfr[ct] = *(const v8s*)(&XS[(ct * 16 + l15) * 136 + ks * 32 + quad * 8]);
      #pragma unroll
      for (int i = 0; i < 2; ++i)
        #pragma unroll
        for (int ct = 0; ct < 4; ++ct)
          acc[i][ct] = MFMA(afr[i], bfr[ct], acc[i][ct]);
    }
    #pragma unroll
    for (int i = 0; i < 2; ++i) {
      int ol0 = (2 * wv + i) * 16 + quad * 4;
      float4 bq = *(const float4*)(bqkv + part * 128 + ol0);
      float bqa[4] = {bq.x, bq.y, bq.z, bq.w};
      #pragma unroll
      for (int ct = 0; ct < 4; ++ct) {
        int token = ct * 16 + l15;
        v4u pk = {f2b(acc[i][ct][0] + bqa[0]), f2b(acc[i][ct][1] + bqa[1]),
                  f2b(acc[i][ct][2] + bqa[2]), f2b(acc[i][ct][3] + bqa[3])};
        if (part == 0)      *(v4u*)(&QP[token * 136 + ol0]) = pk;
        else if (part == 1) *(v4u*)(&KO[token * 136 + ol0]) = pk;
        else                vpk[i][ct] = pk;
      }
    }
  }
  __syncthreads();  // all XS reads done; QP/KO published

  // write V^T over the XS region (overlaps phase 2, published by its barrier)
  #pragma unroll
  for (int i = 0; i < 2; ++i) {
    int ol0 = (2 * wv + i) * 16 + quad * 4;
    #pragma unroll
    for (int ct = 0; ct < 4; ++ct) {
      int token = ct * 16 + l15;
      VT[(ol0 + 0) * 72 + token] = vpk[i][ct][0];
      VT[(ol0 + 1) * 72 + token] = vpk[i][ct][1];
      VT[(ol0 + 2) * 72 + token] = vpk[i][ct][2];
      VT[(ol0 + 3) * 72 + token] = vpk[i][ct][3];
    }
  }

  // phase 2: scores + softmax (wave w owns query tokens 16w..16w+15)
  const int t0 = wv * 16;
  v4f sc[2][4] = {};
  #pragma unroll
  for (int h = 0; h < 2; ++h)
    #pragma unroll
    for (int ks = 0; ks < 2; ++ks) {
      v8s afr = *(const v8s*)(&QP[(t0 + l15) * 136 + h * 64 + ks * 32 + quad * 8]);
      #pragma unroll
      for (int ct = 0; ct < 4; ++ct) {
        v8s bfr = *(const v8s*)(&KO[(ct * 16 + l15) * 136 + h * 64 + ks * 32 + quad * 8]);
        sc[h][ct] = MFMA(afr, bfr, sc[h][ct]);
      }
    }
  float linv[2][4];
  const int rowbase = (t0 + quad * 4) * 64 + l15;
  #pragma unroll
  for (int h = 0; h < 2; ++h) {
    float sv[4][4];
    #pragma unroll
    for (int ct = 0; ct < 4; ++ct)
      #pragma unroll
      for (int r = 0; r < 4; ++r)
        sv[ct][r] = sc[h][ct][r] * 0.125f + bias[rowbase + r * 64 + ct * 16];
    #pragma unroll
    for (int r = 0; r < 4; ++r) {
      float m = fmaxf(fmaxf(sv[0][r], sv[1][r]), fmaxf(sv[2][r], sv[3][r]));
      m = fmaxf(m, __shfl_xor(m, 1, 16));
      m = fmaxf(m, __shfl_xor(m, 2, 16));
      m = fmaxf(m, __shfl_xor(m, 4, 16));
      m = fmaxf(m, __shfl_xor(m, 8, 16));
      float s = 0.f;
      #pragma unroll
      for (int ct = 0; ct < 4; ++ct) { float p = __expf(sv[ct][r] - m); sv[ct][r] = p; s += p; }
      s += __shfl_xor(s, 1, 16);
      s += __shfl_xor(s, 2, 16);
      s += __shfl_xor(s, 4, 16);
      s += __shfl_xor(s, 8, 16);
      linv[h][r] = 1.0f / s;
    }
    #pragma unroll
    for (int ct = 0; ct < 4; ++ct)
      #pragma unroll
      for (int r = 0; r < 4; ++r)
        QP[(t0 + quad * 4 + r) * 136 + h * 64 + ct * 16 + l15] = f2b(sv[ct][r]);
  }
  __syncthreads();  // protects K->O aliasing; publishes VT and P

  // phase 3: O = (P @ V) * 1/l
  v4f ov[2][4] = {};
  #pragma unroll
  for (int h = 0; h < 2; ++h)
    #pragma unroll
    for (int ks = 0; ks < 2; ++ks) {
      v8s afr = *(const v8s*)(&QP[(t0 + l15) * 136 + h * 64 + ks * 32 + quad * 8]);
      #pragma unroll
      for (int ct = 0; ct < 4; ++ct) {
        v8s bfr = *(const v8s*)(&VT[(h * 64 + ct * 16 + l15) * 72 + ks * 32 + quad * 8]);
        ov[h][ct] = MFMA(afr, bfr, ov[h][ct]);
      }
    }
  #pragma unroll
  for (int h = 0; h < 2; ++h)
    #pragma unroll
    for (int ct = 0; ct < 4; ++ct)
      #pragma unroll
      for (int r = 0; r < 4; ++r)
        KO[(t0 + quad * 4 + r) * 136 + h * 64 + ct * 16 + l15] = f2b(ov[h][ct][r] * linv[h][r]);
  // (wave-local: own rows written after own reads; DS in-order per wave)
  __syncthreads();  // all VT reads done before XS (same memory) is overwritten

  // phase 4: head projection + residual (bf16 x from t16, L2-hot); x1 -> XS
  v4f pj[8] = {};
  #pragma unroll
  for (int ks = 0; ks < 4; ++ks) {
    v8s afr = *(const v8s*)(&KO[(t0 + l15) * 136 + ks * 32 + quad * 8]);
    #pragma unroll
    for (int ct = 0; ct < 8; ++ct) {
      v8s bfr = *(const v8s*)(whead_b + (size_t)(ct * 16 + l15) * 128 + ks * 32 + quad * 8);
      pj[ct] = MFMA(afr, bfr, pj[ct]);
    }
  }
  {
    int token0 = t0 + quad * 4;
    int py = token0 >> 3, px = token0 & 7;
    const unsigned short* xtw = t16 + (size_t)((bb * 256 + h0 + py) * 256 + w0 + px) * 128;
    #pragma unroll
    for (int ct = 0; ct < 8; ++ct) {
      int o = ct * 16 + l15;
      float bh = bhead[o];
      #pragma unroll
      for (int r = 0; r < 4; ++r) {
        float xa = b2f(xtw[(size_t)r * 128 + o]);
        XS[(token0 + r) * 136 + o] = f2b(xa + pj[ct][r] + bh);
      }
    }
  }
  __syncthreads();  // all xt reads + XS writes done before the in-place dump

  // dump x1 (bf16 NHWC) over this block's own t16 window (dense 16B/lane)
  #pragma unroll
  for (int it = 0; it < 4; ++it) {
    int idx = it * 256 + tid;
    int token = idx >> 4, c8 = idx & 15;
    int py = token >> 3, px = token & 7;
    *(v8s*)(t16 + (size_t)((bb * 256 + h0 + py) * 256 + w0 + px) * 128 + c8 * 8) =
        *(const v8s*)(&XS[token * 136 + c8 * 8]);
  }
}

// ------- fused conv1(1x1)+GELU + conv2(3x3, edge pad) + LeakyReLU + residual -------
// Tile = 32w x 2h x 128c. Loads x1 halo (136 px) from t16, recomputes
// y = gelu(W1.x1 + b1) in-kernel with fast GELU (no erff), 3x3 MFMA loop.
// LDS: YH ALIASES XH -> 39168 B. __launch_bounds__(256,3): 3 blocks/CU with
// VGPR cap ~170 -- the kernel needs ~128 (yacc[2][9]=72 + acc + frags); the
// R8 bound of 4 forced 64 VGPRs and spilled ~500 MB of scratch traffic.
__global__ __launch_bounds__(256, 3) void conv2_kernel(
    const unsigned short* __restrict__ w2r, const unsigned short* __restrict__ wc1_b,
    const unsigned short* __restrict__ t16,
    const float* __restrict__ bc1, const float* __restrict__ bc2, float* __restrict__ xo) {
  __shared__ unsigned short XH[144 * 136];  // x1 halo [px][c]; later y halo (39168 B)
  unsigned short* const YH = XH;            // alias (barrier discipline below)
  const int tid = threadIdx.x;
  const int wv = tid >> 6, lane = tid & 63, quad = lane >> 4, l15 = lane & 15;
  const int bid0 = blockIdx.x;
  const int bid = ((bid0 & 7) << 9) | (bid0 >> 3);  // XCD swizzle (4096 = 8x512)
  const int bb = bid >> 10, rem = bid & 1023;
  const int y0 = (rem >> 3) * 2, x0 = (rem & 7) * 32;

  // prefetch x1 residual (bf16 NHWC): 4 consecutive channels per (i,ct)
  v4u xpre[2][4];
  #pragma unroll
  for (int i = 0; i < 2; ++i) {
    int o0 = (2 * wv + i) * 16 + quad * 4;
    #pragma unroll
    for (int ct = 0; ct < 4; ++ct) {
      int pix = ct * 16 + l15, typ = pix >> 5, txp = pix & 31;
      xpre[i][ct] = *(const v4u*)(t16 + (size_t)((bb * 256 + y0 + typ) * 256 + x0 + txp) * 128 + o0);
    }
  }

  // x1 halo load: 4 rows x 34 px x 128 ch (edge-clamped), 2176 8ch-units
  for (int it = 0; it < 9; ++it) {
    int idx = it * 256 + tid;
    if (idx < 2176) {
      int hp = idx >> 4, c8 = idx & 15;
      int iy = hp / 34, ix = hp - iy * 34;
      int hy = y0 - 1 + iy; hy = hy < 0 ? 0 : (hy > 255 ? 255 : hy);
      int hx = x0 - 1 + ix; hx = hx < 0 ? 0 : (hx > 255 ? 255 : hx);
      *(v8s*)(&XH[hp * 136 + c8 * 8]) =
          *(const v8s*)(t16 + (size_t)((bb * 256 + hy) * 256 + hx) * 128 + c8 * 8);
    }
  }
  __syncthreads();

  // conv1: yacc[o][px] = W1.x1 for all 136 halo px (9 px-tiles of 16).
  // All XH reads complete here (into registers) before YH overwrites XH.
  v4f yacc[2][9] = {};
  #pragma unroll
  for (int ks = 0; ks < 4; ++ks) {
    v8s afr[2];
    #pragma unroll
    for (int i = 0; i < 2; ++i)
      afr[i] = *(const v8s*)(wc1_b + (size_t)((2 * wv + i) * 16 + l15) * 128 + ks * 32 + quad * 8);
    v8s bfr[9];
    #pragma unroll
    for (int ct = 0; ct < 9; ++ct)
      bfr[ct] = *(const v8s*)(&XH[(ct * 16 + l15) * 136 + ks * 32 + quad * 8]);
    #pragma unroll
    for (int i = 0; i < 2; ++i)
      #pragma unroll
      for (int ct = 0; ct < 9; ++ct)
        yacc[i][ct] = MFMA(afr[i], bfr[ct], yacc[i][ct]);
  }
  __syncthreads();  // all XH reads drained; safe to overwrite with y

  #pragma unroll
  for (int i = 0; i < 2; ++i) {
    int ol0 = (2 * wv + i) * 16 + quad * 4;
    float4 bq = *(const float4*)(bc1 + ol0);
    float bqa[4] = {bq.x, bq.y, bq.z, bq.w};
    #pragma unroll
    for (int ct = 0; ct < 9; ++ct) {
      int token = ct * 16 + l15;   // <=143, fits buffer
      v4u pk = {f2b(gelu_fast(yacc[i][ct][0] + bqa[0])),
                f2b(gelu_fast(yacc[i][ct][1] + bqa[1])),
                f2b(gelu_fast(yacc[i][ct][2] + bqa[2])),
                f2b(gelu_fast(yacc[i][ct][3] + bqa[3]))};
      *(v4u*)(&YH[token * 136 + ol0]) = pk;
    }
  }
  __syncthreads();

  // conv2 3x3 over YH
  v4f acc[2][4] = {};
  int bct[4];
  #pragma unroll
  for (int ct = 0; ct < 4; ++ct) {
    int pix = ct * 16 + l15, typ = pix >> 5, txp = pix & 31;
    bct[ct] = (typ * 34 + txp) * 136 + quad * 8;
  }
  const unsigned short* wb0 = w2r + (size_t)((2 * wv + 0) * 16 + l15) * 1152 + quad * 8;
  const unsigned short* wb1 = w2r + (size_t)((2 * wv + 1) * 16 + l15) * 1152 + quad * 8;
  #pragma unroll
  for (int ks = 0; ks < 36; ++ks) {
    const int pos = ks >> 2, cb = ks & 3;
    const int ky = pos / 3, kx = pos - ky * 3;
    const int koff = (ky * 34 + kx) * 136 + cb * 32;
    v8s a0 = *(const v8s*)(wb0 + ks * 32);
    v8s a1 = *(const v8s*)(wb1 + ks * 32);
    #pragma unroll
    for (int ct = 0; ct < 4; ++ct) {
      v8s bfr = *(const v8s*)(&YH[bct[ct] + koff]);
      acc[0][ct] = MFMA(a0, bfr, acc[0][ct]);
      acc[1][ct] = MFMA(a1, bfr, acc[1][ct]);
    }
  }

  // epilogue: bias + leaky + bf16 residual, store straight from registers.
  #pragma unroll
  for (int i = 0; i < 2; ++i) {
    int o0 = (2 * wv + i) * 16 + quad * 4;
    float4 bc = *(const float4*)(bc2 + o0);
    float bca[4] = {bc.x, bc.y, bc.z, bc.w};
    #pragma unroll
    for (int ct = 0; ct < 4; ++ct) {
      int pix = ct * 16 + l15, typ = pix >> 5, txp = pix & 31;
      float* po = xo + (size_t)(bb * 128 + o0) * 65536 + (y0 + typ) * 256 + (x0 + txp);
      #pragma unroll
      for (int r = 0; r < 4; ++r) {
        float v = acc[i][ct][r] + bca[r];
        v = v > 0.f ? v : 0.1f * v;
        po[(size_t)r * 65536] = v + b2f(xpre[i][ct][r]);
      }
    }
  }
}

extern "C" void kernel_launch(void* const* d_in, const int* in_sizes, int n_in,
                              void* d_out, int out_size, void* d_ws, size_t ws_size,
                              hipStream_t stream) {
  (void)in_sizes; (void)n_in; (void)out_size; (void)ws_size;
  const float* x      = (const float*)d_in[0];
  const float* delta  = (const float*)d_in[1];
  const int*   indexv = (const int*)d_in[2];
  const float* w_qkv  = (const float*)d_in[3];
  const float* b_qkv  = (const float*)d_in[4];
  const float* w_head = (const float*)d_in[5];
  const float* b_head = (const float*)d_in[6];
  const float* w_b1   = (const float*)d_in[7];
  const float* b_b1   = (const float*)d_in[8];
  const float* w_b2   = (const float*)d_in[9];
  const float* b_b2   = (const float*)d_in[10];
  const float* w_c1   = (const float*)d_in[11];
  const float* b_c1   = (const float*)d_in[12];
  const float* w_c2   = (const float*)d_in[13];
  const float* b_c2   = (const float*)d_in[14];
  float* out = (float*)d_out;

  char* ws = (char*)d_ws;
  float*          bias_ws = (float*)(ws + 0);                 //  16384 B
  unsigned short* wqkv_b  = (unsigned short*)(ws + 16384);    //  98304 B
  unsigned short* whead_b = (unsigned short*)(ws + 114688);   //  32768 B
  unsigned short* wc1_b   = (unsigned short*)(ws + 147456);   //  32768 B
  unsigned short* w2r_b   = (unsigned short*)(ws + 180224);   // 294912 B
  unsigned short* t16     = (unsigned short*)(ws + 475136 + 67108864); // 67108864 B: bf16(x) -> x1

  prep_kernel<<<912, 256, 0, stream>>>(w_qkv, w_head, w_c1, w_c2, delta, indexv,
                                       w_b1, b_b1, w_b2, b_b2,
                                       wqkv_b, whead_b, wc1_b, w2r_b, bias_ws);
  xt_kernel<<<1024, 256, 0, stream>>>(x, t16);
  attn_kernel<<<4096, 256, 0, stream>>>(bias_ws, wqkv_b, whead_b,
                                        b_qkv, b_head, t16);
  conv2_kernel<<<4096, 256, 0, stream>>>(w2r_b, wc1_b, t16, b_c1, b_c2, out);
}

// Round 10
// 572.336 us; speedup vs baseline: 1.1348x; 1.0005x over previous
//
#include <hip/hip_runtime.h>

typedef short v8s __attribute__((ext_vector_type(8)));
typedef float v4f __attribute__((ext_vector_type(4)));
typedef unsigned short v4u __attribute__((ext_vector_type(4)));

#define MFMA(a,b,c) __builtin_amdgcn_mfma_f32_16x16x32_bf16((a),(b),(c),0,0,0)

__device__ __forceinline__ unsigned short f2b(float f) {
  unsigned int x = __builtin_bit_cast(unsigned int, f);
  x += 0x7fffu + ((x >> 16) & 1u);
  return (unsigned short)(x >> 16);
}

__device__ __forceinline__ float b2f(unsigned short u) {
  unsigned int x = ((unsigned int)u) << 16;
  return __builtin_bit_cast(float, x);
}

// hardware packed f32x2 -> bf16x2 (RNE), one VALU instr instead of ~8
__device__ __forceinline__ unsigned int cvtpk(float lo, float hi) {
  unsigned int r;
  asm("v_cvt_pk_bf16_f32 %0, %1, %2" : "=v"(r) : "v"(lo), "v"(hi));
  return r;
}

__device__ __forceinline__ float gelu_exact(float v) {
  return 0.5f * v * (1.0f + erff(v * 0.70710678118654752f));
}

// fast GELU (tanh form via sigmoid): max |err| ~3e-4, << bf16 rounding of y
__device__ __forceinline__ float gelu_fast(float v) {
  float u = 1.5957691f * v * (1.0f + 0.044715f * v * v);
  return v * (1.0f / (1.0f + __expf(-u)));
}

// ---------------- prep: weight bf16 conversion + bias MLP ----------------
__global__ void prep_kernel(const float* __restrict__ wqkv, const float* __restrict__ whead,
                            const float* __restrict__ wc1, const float* __restrict__ wc2,
                            const float* __restrict__ delta, const int* __restrict__ indexv,
                            const float* __restrict__ wb1, const float* __restrict__ bb1,
                            const float* __restrict__ wb2, const float* __restrict__ bb2,
                            unsigned short* __restrict__ wqkv_b, unsigned short* __restrict__ whead_b,
                            unsigned short* __restrict__ wc1_b, unsigned short* __restrict__ w2r_b,
                            float* __restrict__ bias_ws) {
  int i = blockIdx.x * 256 + threadIdx.x;
  if (i < 49152) { wqkv_b[i] = f2b(wqkv[i]); return; }
  i -= 49152;
  if (i < 16384) { whead_b[i] = f2b(whead[i]); return; }
  i -= 16384;
  if (i < 16384) { wc1_b[i] = f2b(wc1[i]); return; }
  i -= 16384;
  if (i < 147456) {
    // dst layout: w2r[o*1152 + (ky*3+kx)*128 + c]; src: wc2[o*1152 + c*9 + (ky*3+kx)]
    int o = i / 1152; int rem = i - o * 1152; int pos = rem >> 7; int c = rem & 127;
    w2r_b[i] = f2b(wc2[o * 1152 + c * 9 + pos]);
    return;
  }
  i -= 147456;
  if (i < 4096) {
    int u = indexv[i];
    float d0 = delta[2 * u], d1 = delta[2 * u + 1];
    float acc = bb2[0];
    #pragma unroll
    for (int j = 0; j < 16; ++j) {
      float t = d0 * wb1[2 * j] + d1 * wb1[2 * j + 1] + bb1[j];
      acc += gelu_exact(t) * wb2[j];
    }
    bias_ws[i] = acc;
  }
}

// ---------------- x BCHW fp32 -> NHWC bf16 transpose ----------------
// half image row per block (2048 blocks): 33KB LDS -> 4 blocks/CU.
__global__ __launch_bounds__(256, 4) void xt_kernel(
    const float* __restrict__ x, unsigned short* __restrict__ t16) {
  __shared__ unsigned short T[128 * 129];  // [px][c], odd stride (33024 B)
  const int tid = threadIdx.x;
  const int bid = blockIdx.x;              // 2048 = 4 b x 256 h x 2 halves
  const int b = bid >> 9, h = (bid >> 1) & 255, xh = (bid & 1) * 128;
  const float* src = x + (size_t)b * 128 * 65536 + h * 256 + xh;

  #pragma unroll
  for (int it = 0; it < 16; ++it) {
    int u = it * 256 + tid;                // 4096 float4 units
    int c = u >> 5, w4 = u & 31;           // 32 float4 per channel row (512B dense)
    float4 v = *(const float4*)(src + (size_t)c * 65536 + w4 * 4);
    int base = (w4 * 4) * 129 + c;
    T[base]       = f2b(v.x);
    T[base + 129] = f2b(v.y);
    T[base + 258] = f2b(v.z);
    T[base + 387] = f2b(v.w);
  }
  __syncthreads();

  unsigned short* dst = t16 + (size_t)((b * 256 + h) * 256 + xh) * 128;
  #pragma unroll
  for (int it = 0; it < 8; ++it) {
    int idx = it * 256 + tid;              // 2048 v8s units
    int px = idx >> 4, c8 = idx & 15;
    const unsigned short* t = &T[px * 129 + c8 * 8];
    v8s o;
    #pragma unroll
    for (int j = 0; j < 8; ++j) o[j] = (short)t[j];
    *(v8s*)(dst + px * 128 + c8 * 8) = o;
  }
}

// ---------------- fused window-attention ----------------
// one block (256 thr) per 8x8 window; reads bf16(x) from t16 (dense NHWC),
// overwrites its own t16 window with x1 (bf16). conv1 lives in conv2.
// LDS: XS aliases VT -> 53248 B -> 3 blocks/CU.
__global__ __launch_bounds__(256, 3) void attn_kernel(
    const float* __restrict__ bias,
    const unsigned short* __restrict__ wqkv_b, const unsigned short* __restrict__ whead_b,
    const float* __restrict__ bqkv, const float* __restrict__ bhead,
    unsigned short* __restrict__ t16) {
  __shared__ unsigned short U0[128 * 72];   // VT [c][token]  (18432 B)
                                            // aliased: XS [token][136] bf16 x, later bf16 x1
  __shared__ unsigned short QP[64 * 136];   // Q [token][c]; later P [token][h*64+m]
  __shared__ unsigned short KO[64 * 136];   // K [token][c]; later O [token][c]
  unsigned short* const XS = U0;
  unsigned short* const VT = U0;

  const int tid = threadIdx.x;
  const int wv = tid >> 6, lane = tid & 63, quad = lane >> 4, l15 = lane & 15;
  // XCD-aware swizzle: grid 4096 = 8 XCDs x 512 contiguous windows each
  const int bid0 = blockIdx.x;
  const int bid = ((bid0 & 7) << 9) | (bid0 >> 3);
  const int bb = bid >> 10, rem = bid & 1023;
  const int h0 = (rem >> 5) * 8, w0 = (rem & 31) * 8;

  // phase 0: load x window (bf16 NHWC) -> XS, dense 16B/lane
  #pragma unroll
  for (int it = 0; it < 4; ++it) {
    int idx = it * 256 + tid;
    int token = idx >> 4, c8 = idx & 15;
    int py = token >> 3, px = token & 7;
    *(v8s*)(&XS[token * 136 + c8 * 8]) =
        *(const v8s*)(t16 + (size_t)((bb * 256 + h0 + py) * 256 + w0 + px) * 128 + c8 * 8);
  }
  __syncthreads();

  // phase 1: QKV GEMM (M = out-channel, N = token, K = c)
  const int t0 = wv * 16;
  v4u vpk[2][4];
  #pragma unroll
  for (int part = 0; part < 3; ++part) {
    v4f acc[2][4] = {};
    #pragma unroll
    for (int ks = 0; ks < 4; ++ks) {
      v8s afr[2];
      #pragma unroll
      for (int i = 0; i < 2; ++i)
        afr[i] = *(const v8s*)(wqkv_b + (size_t)(part * 128 + (2 * wv + i) * 16 + l15) * 128 + ks * 32 + quad * 8);
      v8s bfr[4];
      #pragma unroll
      for (int ct = 0; ct < 4; ++ct)
        bfr[ct] = *(const v8s*)(&XS[(ct * 16 + l15) * 136 + ks * 32 + quad * 8]);
      #pragma unroll
      for (int i = 0; i < 2; ++i)
        #pragma unroll
        for (int ct = 0; ct < 4; ++ct)
          acc[i][ct] = MFMA(afr[i], bfr[ct], acc[i][ct]);
    }
    #pragma unroll
    for (int i = 0; i < 2; ++i) {
      int ol0 = (2 * wv + i) * 16 + quad * 4;
      float4 bq = *(const float4*)(bqkv + part * 128 + ol0);
      float bqa[4] = {bq.x, bq.y, bq.z, bq.w};
      #pragma unroll
      for (int ct = 0; ct < 4; ++ct) {
        int token = ct * 16 + l15;
        if (part < 2) {
          uint2 pk2;
          pk2.x = cvtpk(acc[i][ct][0] + bqa[0], acc[i][ct][1] + bqa[1]);
          pk2.y = cvtpk(acc[i][ct][2] + bqa[2], acc[i][ct][3] + bqa[3]);
          if (part == 0) *(uint2*)(&QP[token * 136 + ol0]) = pk2;
          else           *(uint2*)(&KO[token * 136 + ol0]) = pk2;
        } else {
          v4u pk = {f2b(acc[i][ct][0] + bqa[0]), f2b(acc[i][ct][1] + bqa[1]),
                    f2b(acc[i][ct][2] + bqa[2]), f2b(acc[i][ct][3] + bqa[3])};
          vpk[i][ct] = pk;
        }
      }
    }
  }

  // stash residual x (bf16) in registers before V^T overwrites XS.
  // layout matches phase-4's (token0+r, o) ownership.
  unsigned short xres[8][4];
  {
    int token0 = t0 + quad * 4;
    #pragma unroll
    for (int ct = 0; ct < 8; ++ct) {
      int o = ct * 16 + l15;
      #pragma unroll
      for (int r = 0; r < 4; ++r) xres[ct][r] = XS[(token0 + r) * 136 + o];
    }
  }
  __syncthreads();  // all XS reads done; QP/KO published

  // write V^T over the XS region (overlaps phase 2, published by its barrier)
  #pragma unroll
  for (int i = 0; i < 2; ++i) {
    int ol0 = (2 * wv + i) * 16 + quad * 4;
    #pragma unroll
    for (int ct = 0; ct < 4; ++ct) {
      int token = ct * 16 + l15;
      VT[(ol0 + 0) * 72 + token] = vpk[i][ct][0];
      VT[(ol0 + 1) * 72 + token] = vpk[i][ct][1];
      VT[(ol0 + 2) * 72 + token] = vpk[i][ct][2];
      VT[(ol0 + 3) * 72 + token] = vpk[i][ct][3];
    }
  }

  // phase 2: scores + softmax (wave w owns query tokens 16w..16w+15)
  v4f sc[2][4] = {};
  #pragma unroll
  for (int h = 0; h < 2; ++h)
    #pragma unroll
    for (int ks = 0; ks < 2; ++ks) {
      v8s afr = *(const v8s*)(&QP[(t0 + l15) * 136 + h * 64 + ks * 32 + quad * 8]);
      #pragma unroll
      for (int ct = 0; ct < 4; ++ct) {
        v8s bfr = *(const v8s*)(&KO[(ct * 16 + l15) * 136 + h * 64 + ks * 32 + quad * 8]);
        sc[h][ct] = MFMA(afr, bfr, sc[h][ct]);
      }
    }
  float linv[2][4];
  const int rowbase = (t0 + quad * 4) * 64 + l15;
  #pragma unroll
  for (int h = 0; h < 2; ++h) {
    float sv[4][4];
    #pragma unroll
    for (int ct = 0; ct < 4; ++ct)
      #pragma unroll
      for (int r = 0; r < 4; ++r)
        sv[ct][r] = sc[h][ct][r] * 0.125f + bias[rowbase + r * 64 + ct * 16];
    #pragma unroll
    for (int r = 0; r < 4; ++r) {
      float m = fmaxf(fmaxf(sv[0][r], sv[1][r]), fmaxf(sv[2][r], sv[3][r]));
      m = fmaxf(m, __shfl_xor(m, 1, 16));
      m = fmaxf(m, __shfl_xor(m, 2, 16));
      m = fmaxf(m, __shfl_xor(m, 4, 16));
      m = fmaxf(m, __shfl_xor(m, 8, 16));
      float s = 0.f;
      #pragma unroll
      for (int ct = 0; ct < 4; ++ct) { float p = __expf(sv[ct][r] - m); sv[ct][r] = p; s += p; }
      s += __shfl_xor(s, 1, 16);
      s += __shfl_xor(s, 2, 16);
      s += __shfl_xor(s, 4, 16);
      s += __shfl_xor(s, 8, 16);
      linv[h][r] = 1.0f / s;
    }
    #pragma unroll
    for (int ct = 0; ct < 4; ++ct)
      #pragma unroll
      for (int r = 0; r < 4; ++r)
        QP[(t0 + quad * 4 + r) * 136 + h * 64 + ct * 16 + l15] = f2b(sv[ct][r]);
  }
  __syncthreads();  // protects K->O aliasing; publishes VT and P

  // phase 3: O = (P @ V) * 1/l
  v4f ov[2][4] = {};
  #pragma unroll
  for (int h = 0; h < 2; ++h)
    #pragma unroll
    for (int ks = 0; ks < 2; ++ks) {
      v8s afr = *(const v8s*)(&QP[(t0 + l15) * 136 + h * 64 + ks * 32 + quad * 8]);
      #pragma unroll
      for (int ct = 0; ct < 4; ++ct) {
        v8s bfr = *(const v8s*)(&VT[(h * 64 + ct * 16 + l15) * 72 + ks * 32 + quad * 8]);
        ov[h][ct] = MFMA(afr, bfr, ov[h][ct]);
      }
    }
  #pragma unroll
  for (int h = 0; h < 2; ++h)
    #pragma unroll
    for (int ct = 0; ct < 4; ++ct)
      #pragma unroll
      for (int r = 0; r < 4; ++r)
        KO[(t0 + quad * 4 + r) * 136 + h * 64 + ct * 16 + l15] = f2b(ov[h][ct][r] * linv[h][r]);
  // (wave-local: own rows written after own reads; DS in-order per wave)
  __syncthreads();

  // phase 4: head projection + residual (x from xres registers); x1 -> XS
  v4f pj[8] = {};
  #pragma unroll
  for (int ks = 0; ks < 4; ++ks) {
    v8s afr = *(const v8s*)(&KO[(t0 + l15) * 136 + ks * 32 + quad * 8]);
    #pragma unroll
    for (int ct = 0; ct < 8; ++ct) {
      v8s bfr = *(const v8s*)(whead_b + (size_t)(ct * 16 + l15) * 128 + ks * 32 + quad * 8);
      pj[ct] = MFMA(afr, bfr, pj[ct]);
    }
  }
  {
    int token0 = t0 + quad * 4;
    #pragma unroll
    for (int ct = 0; ct < 8; ++ct) {
      int o = ct * 16 + l15;
      float bh = bhead[o];
      #pragma unroll
      for (int r = 0; r < 4; ++r)
        XS[(token0 + r) * 136 + o] = f2b(b2f(xres[ct][r]) + pj[ct][r] + bh);
    }
  }
  __syncthreads();  // all XS writes done before the in-place dump

  // dump x1 (bf16 NHWC) over this block's own t16 window (dense 16B/lane)
  #pragma unroll
  for (int it = 0; it < 4; ++it) {
    int idx = it * 256 + tid;
    int token = idx >> 4, c8 = idx & 15;
    int py = token >> 3, px = token & 7;
    *(v8s*)(t16 + (size_t)((bb * 256 + h0 + py) * 256 + w0 + px) * 128 + c8 * 8) =
        *(const v8s*)(&XS[token * 136 + c8 * 8]);
  }
}

// ------- fused conv1(1x1)+GELU + conv2(3x3, edge pad) + LeakyReLU + residual -------
// Tile = 32w x 2h x 128c. Loads x1 halo (136 px) from t16, recomputes
// y = gelu(W1.x1 + b1) in-kernel (fast GELU + cvt_pk packing), 3x3 MFMA loop.
// LDS: YH ALIASES XH -> 39168 B; launch_bounds(256,3) keeps VGPRs unspilled.
__global__ __launch_bounds__(256, 3) void conv2_kernel(
    const unsigned short* __restrict__ w2r, const unsigned short* __restrict__ wc1_b,
    const unsigned short* __restrict__ t16,
    const float* __restrict__ bc1, const float* __restrict__ bc2, float* __restrict__ xo) {
  __shared__ unsigned short XH[144 * 136];  // x1 halo [px][c]; later y halo (39168 B)
  unsigned short* const YH = XH;            // alias (barrier discipline below)
  const int tid = threadIdx.x;
  const int wv = tid >> 6, lane = tid & 63, quad = lane >> 4, l15 = lane & 15;
  const int bid0 = blockIdx.x;
  const int bid = ((bid0 & 7) << 9) | (bid0 >> 3);  // XCD swizzle (4096 = 8x512)
  const int bb = bid >> 10, rem = bid & 1023;
  const int y0 = (rem >> 3) * 2, x0 = (rem & 7) * 32;

  // prefetch x1 residual (bf16 NHWC): 4 consecutive channels per (i,ct)
  v4u xpre[2][4];
  #pragma unroll
  for (int i = 0; i < 2; ++i) {
    int o0 = (2 * wv + i) * 16 + quad * 4;
    #pragma unroll
    for (int ct = 0; ct < 4; ++ct) {
      int pix = ct * 16 + l15, typ = pix >> 5, txp = pix & 31;
      xpre[i][ct] = *(const v4u*)(t16 + (size_t)((bb * 256 + y0 + typ) * 256 + x0 + txp) * 128 + o0);
    }
  }

  // x1 halo load: 4 rows x 34 px x 128 ch (edge-clamped), 2176 8ch-units
  for (int it = 0; it < 9; ++it) {
    int idx = it * 256 + tid;
    if (idx < 2176) {
      int hp = idx >> 4, c8 = idx & 15;
      int iy = hp / 34, ix = hp - iy * 34;
      int hy = y0 - 1 + iy; hy = hy < 0 ? 0 : (hy > 255 ? 255 : hy);
      int hx = x0 - 1 + ix; hx = hx < 0 ? 0 : (hx > 255 ? 255 : hx);
      *(v8s*)(&XH[hp * 136 + c8 * 8]) =
          *(const v8s*)(t16 + (size_t)((bb * 256 + hy) * 256 + hx) * 128 + c8 * 8);
    }
  }
  __syncthreads();

  // conv1: yacc[o][px] = W1.x1 for all 136 halo px (9 px-tiles of 16).
  // All XH reads complete here (into registers) before YH overwrites XH.
  v4f yacc[2][9] = {};
  #pragma unroll
  for (int ks = 0; ks < 4; ++ks) {
    v8s afr[2];
    #pragma unroll
    for (int i = 0; i < 2; ++i)
      afr[i] = *(const v8s*)(wc1_b + (size_t)((2 * wv + i) * 16 + l15) * 128 + ks * 32 + quad * 8);
    v8s bfr[9];
    #pragma unroll
    for (int ct = 0; ct < 9; ++ct)
      bfr[ct] = *(const v8s*)(&XH[(ct * 16 + l15) * 136 + ks * 32 + quad * 8]);
    #pragma unroll
    for (int i = 0; i < 2; ++i)
      #pragma unroll
      for (int ct = 0; ct < 9; ++ct)
        yacc[i][ct] = MFMA(afr[i], bfr[ct], yacc[i][ct]);
  }
  __syncthreads();  // all XH reads drained; safe to overwrite with y

  #pragma unroll
  for (int i = 0; i < 2; ++i) {
    int ol0 = (2 * wv + i) * 16 + quad * 4;
    float4 bq = *(const float4*)(bc1 + ol0);
    float bqa[4] = {bq.x, bq.y, bq.z, bq.w};
    #pragma unroll
    for (int ct = 0; ct < 9; ++ct) {
      int token = ct * 16 + l15;   // <=143, fits buffer
      uint2 pk2;
      pk2.x = cvtpk(gelu_fast(yacc[i][ct][0] + bqa[0]), gelu_fast(yacc[i][ct][1] + bqa[1]));
      pk2.y = cvtpk(gelu_fast(yacc[i][ct][2] + bqa[2]), gelu_fast(yacc[i][ct][3] + bqa[3]));
      *(uint2*)(&YH[token * 136 + ol0]) = pk2;
    }
  }
  __syncthreads();

  // conv2 3x3 over YH
  v4f acc[2][4] = {};
  int bct[4];
  #pragma unroll
  for (int ct = 0; ct < 4; ++ct) {
    int pix = ct * 16 + l15, typ = pix >> 5, txp = pix & 31;
    bct[ct] = (typ * 34 + txp) * 136 + quad * 8;
  }
  const unsigned short* wb0 = w2r + (size_t)((2 * wv + 0) * 16 + l15) * 1152 + quad * 8;
  const unsigned short* wb1 = w2r + (size_t)((2 * wv + 1) * 16 + l15) * 1152 + quad * 8;
  #pragma unroll
  for (int ks = 0; ks < 36; ++ks) {
    const int pos = ks >> 2, cb = ks & 3;
    const int ky = pos / 3, kx = pos - ky * 3;
    const int koff = (ky * 34 + kx) * 136 + cb * 32;
    v8s a0 = *(const v8s*)(wb0 + ks * 32);
    v8s a1 = *(const v8s*)(wb1 + ks * 32);
    #pragma unroll
    for (int ct = 0; ct < 4; ++ct) {
      v8s bfr = *(const v8s*)(&YH[bct[ct] + koff]);
      acc[0][ct] = MFMA(a0, bfr, acc[0][ct]);
      acc[1][ct] = MFMA(a1, bfr, acc[1][ct]);
    }
  }

  // epilogue: bias + leaky + bf16 residual, store straight from registers.
  #pragma unroll
  for (int i = 0; i < 2; ++i) {
    int o0 = (2 * wv + i) * 16 + quad * 4;
    float4 bc = *(const float4*)(bc2 + o0);
    float bca[4] = {bc.x, bc.y, bc.z, bc.w};
    #pragma unroll
    for (int ct = 0; ct < 4; ++ct) {
      int pix = ct * 16 + l15, typ = pix >> 5, txp = pix & 31;
      float* po = xo + (size_t)(bb * 128 + o0) * 65536 + (y0 + typ) * 256 + (x0 + txp);
      #pragma unroll
      for (int r = 0; r < 4; ++r) {
        float v = acc[i][ct][r] + bca[r];
        v = v > 0.f ? v : 0.1f * v;
        po[(size_t)r * 65536] = v + b2f(xpre[i][ct][r]);
      }
    }
  }
}

extern "C" void kernel_launch(void* const* d_in, const int* in_sizes, int n_in,
                              void* d_out, int out_size, void* d_ws, size_t ws_size,
                              hipStream_t stream) {
  (void)in_sizes; (void)n_in; (void)out_size; (void)ws_size;
  const float* x      = (const float*)d_in[0];
  const float* delta  = (const float*)d_in[1];
  const int*   indexv = (const int*)d_in[2];
  const float* w_qkv  = (const float*)d_in[3];
  const float* b_qkv  = (const float*)d_in[4];
  const float* w_head = (const float*)d_in[5];
  const float* b_head = (const float*)d_in[6];
  const float* w_b1   = (const float*)d_in[7];
  const float* b_b1   = (const float*)d_in[8];
  const float* w_b2   = (const float*)d_in[9];
  const float* b_b2   = (const float*)d_in[10];
  const float* w_c1   = (const float*)d_in[11];
  const float* b_c1   = (const float*)d_in[12];
  const float* w_c2   = (const float*)d_in[13];
  const float* b_c2   = (const float*)d_in[14];
  float* out = (float*)d_out;

  char* ws = (char*)d_ws;
  float*          bias_ws = (float*)(ws + 0);                 //  16384 B
  unsigned short* wqkv_b  = (unsigned short*)(ws + 16384);    //  98304 B
  unsigned short* whead_b = (unsigned short*)(ws + 114688);   //  32768 B
  unsigned short* wc1_b   = (unsigned short*)(ws + 147456);   //  32768 B
  unsigned short* w2r_b   = (unsigned short*)(ws + 180224);   // 294912 B
  unsigned short* t16     = (unsigned short*)(ws + 475136 + 67108864); // 67108864 B: bf16(x) -> x1

  prep_kernel<<<912, 256, 0, stream>>>(w_qkv, w_head, w_c1, w_c2, delta, indexv,
                                       w_b1, b_b1, w_b2, b_b2,
                                       wqkv_b, whead_b, wc1_b, w2r_b, bias_ws);
  xt_kernel<<<2048, 256, 0, stream>>>(x, t16);
  attn_kernel<<<4096, 256, 0, stream>>>(bias_ws, wqkv_b, whead_b,
                                        b_qkv, b_head, t16);
  conv2_kernel<<<4096, 256, 0, stream>>>(w2r_b, wc1_b, t16, b_c1, b_c2, out);
}